// Round 1
// baseline (144.986 us; speedup 1.0000x reference)
//
#include <hip/hip_runtime.h>

#define D 128

__global__ __launch_bounds__(128) void transr_loss_kernel(
    const float* __restrict__ ent,
    const float* __restrict__ rel,
    const float* __restrict__ tmat,
    const int* __restrict__ pos_h,
    const int* __restrict__ pos_t,
    const int* __restrict__ pos_r,
    const int* __restrict__ pos_type_r,
    const int* __restrict__ neg_h,
    const int* __restrict__ neg_t,
    const int* __restrict__ neg_r,
    float* __restrict__ out,
    int B)
{
    const int b = blockIdx.x;
    const int r = threadIdx.x;          // 0..127, output column
    const int lane = r & 63;
    const int wid = r >> 6;

    __shared__ float4 vcomb[D];         // {p_h, p_t, n_h, n_t}[d]
    __shared__ float sred[16];

    // gathers (coalesced: thread r reads element r of each row)
    const float* ph = ent + (size_t)pos_h[b] * D;
    const float* pt = ent + (size_t)pos_t[b] * D;
    const float* nh = ent + (size_t)neg_h[b] * D;
    const float* nt = ent + (size_t)neg_t[b] * D;
    vcomb[r] = make_float4(ph[r], pt[r], nh[r], nt[r]);
    const float prr = rel[(size_t)pos_r[b] * D + r];
    const float nrr = rel[(size_t)neg_r[b] * D + r];
    __syncthreads();

    // 4 vec-mat products sharing each T element:
    // out[r] = sum_d v[d] * T[d*128 + r]
    const float* __restrict__ T = tmat + (size_t)pos_type_r[b] * (D * D);
    float aph = 0.f, apt = 0.f, anh = 0.f, ant = 0.f;
    #pragma unroll 8
    for (int d = 0; d < D; ++d) {
        const float t = T[d * D + r];
        const float4 v = vcomb[d];
        aph = fmaf(v.x, t, aph);
        apt = fmaf(v.y, t, apt);
        anh = fmaf(v.z, t, anh);
        ant = fmaf(v.w, t, ant);
    }

    // block-reduce 6 sums of squares
    float s0 = aph * aph, s1 = apt * apt, s2 = anh * anh, s3 = ant * ant;
    float s4 = prr * prr, s5 = nrr * nrr;
    #pragma unroll
    for (int off = 32; off; off >>= 1) {
        s0 += __shfl_xor(s0, off);
        s1 += __shfl_xor(s1, off);
        s2 += __shfl_xor(s2, off);
        s3 += __shfl_xor(s3, off);
        s4 += __shfl_xor(s4, off);
        s5 += __shfl_xor(s5, off);
    }
    if (lane == 0) {
        sred[wid * 8 + 0] = s0; sred[wid * 8 + 1] = s1;
        sred[wid * 8 + 2] = s2; sred[wid * 8 + 3] = s3;
        sred[wid * 8 + 4] = s4; sred[wid * 8 + 5] = s5;
    }
    __syncthreads();
    const float inv_ph = rsqrtf(sred[0] + sred[8]  + 1e-12f);
    const float inv_pt = rsqrtf(sred[1] + sred[9]  + 1e-12f);
    const float inv_nh = rsqrtf(sred[2] + sred[10] + 1e-12f);
    const float inv_nt = rsqrtf(sred[3] + sred[11] + 1e-12f);
    const float inv_pr = rsqrtf(sred[4] + sred[12] + 1e-12f);
    const float inv_nr = rsqrtf(sred[5] + sred[13] + 1e-12f);

    // score terms
    float pterm = fabsf(aph * inv_ph + prr * inv_pr - apt * inv_pt);
    float nterm = fabsf(anh * inv_nh + nrr * inv_nr - ant * inv_nt);
    #pragma unroll
    for (int off = 32; off; off >>= 1) {
        pterm += __shfl_xor(pterm, off);
        nterm += __shfl_xor(nterm, off);
    }
    __syncthreads();   // sred reuse guard
    if (lane == 0) { sred[wid * 2 + 0] = pterm; sred[wid * 2 + 1] = nterm; }
    __syncthreads();
    if (r == 0) {
        const float p = sred[0] + sred[2];
        const float n = sred[1] + sred[3];
        const float hinge = fmaxf(p - n + 1.0f, 0.0f);
        atomicAdd(out, hinge * (1.0f / (float)B));
    }
}

extern "C" void kernel_launch(void* const* d_in, const int* in_sizes, int n_in,
                              void* d_out, int out_size, void* d_ws, size_t ws_size,
                              hipStream_t stream) {
    const float* ent  = (const float*)d_in[0];
    const float* rel  = (const float*)d_in[1];
    const float* tmat = (const float*)d_in[2];
    const int* pos_h      = (const int*)d_in[3];
    const int* pos_t      = (const int*)d_in[4];
    const int* pos_r      = (const int*)d_in[5];
    const int* pos_type_r = (const int*)d_in[6];
    const int* neg_h      = (const int*)d_in[7];
    const int* neg_t      = (const int*)d_in[8];
    const int* neg_r      = (const int*)d_in[9];
    float* out = (float*)d_out;
    const int B = in_sizes[3];

    hipMemsetAsync(out, 0, sizeof(float), stream);
    transr_loss_kernel<<<B, 128, 0, stream>>>(
        ent, rel, tmat, pos_h, pos_t, pos_r, pos_type_r,
        neg_h, neg_t, neg_r, out, B);
}

// Round 2
// 76.228 us; speedup vs baseline: 1.9020x; 1.9020x over previous
//
#include <hip/hip_runtime.h>

#define D 128
#define CHUNK 8
#define MAX_TYPES 1024
#define MAX_ITEMS 2048
#define MARGIN 1.0f

// ws layout (int units):
// [0,1024)      counts
// [1024,2048)   cursor
// [2048]        n_items
// [4096,12288)  order (sample indices grouped by type)
// [16384,24576) items (int4 x 2048: {type, start, cnt, pad})
#define WS_COUNTS 0
#define WS_CURSOR 1024
#define WS_NITEMS 2048
#define WS_ORDER  4096
#define WS_ITEMS  16384
#define WS_NEEDED ((size_t)(24576 * 4))

// ---------------- aux kernels ----------------

__global__ void hist_kernel(const int* __restrict__ type_r, int* __restrict__ ws, int B) {
    int i = blockIdx.x * blockDim.x + threadIdx.x;
    if (i < B) atomicAdd(&ws[WS_COUNTS + type_r[i]], 1);
}

__global__ __launch_bounds__(1024) void scan_kernel(int* __restrict__ ws, int ntype) {
    __shared__ int a[1024];
    const int tid = threadIdx.x;
    const int c = (tid < ntype) ? ws[WS_COUNTS + tid] : 0;
    a[tid] = c;
    __syncthreads();
    int v = c;
    #pragma unroll
    for (int off = 1; off < 1024; off <<= 1) {
        int t = v;
        int add = (tid >= off) ? a[tid - off] : 0;
        __syncthreads();
        v = t + add;
        a[tid] = v;
        __syncthreads();
    }
    const int excl = v - c;
    if (tid < ntype) ws[WS_CURSOR + tid] = excl;

    // second scan: item counts
    const int ic = (c + CHUNK - 1) / CHUNK;
    a[tid] = ic;
    __syncthreads();
    int iv = ic;
    #pragma unroll
    for (int off = 1; off < 1024; off <<= 1) {
        int t = iv;
        int add = (tid >= off) ? a[tid - off] : 0;
        __syncthreads();
        iv = t + add;
        a[tid] = iv;
        __syncthreads();
    }
    const int iexcl = iv - ic;
    if (tid < ntype) {
        int4* items = (int4*)(ws + WS_ITEMS);
        for (int i = 0; i < ic; ++i)
            items[iexcl + i] = make_int4(tid, excl + i * CHUNK, min(CHUNK, c - i * CHUNK), 0);
    }
    if (tid == 1023) ws[WS_NITEMS] = iv;
}

__global__ void scatter_kernel(const int* __restrict__ type_r, int* __restrict__ ws, int B) {
    int i = blockIdx.x * blockDim.x + threadIdx.x;
    if (i < B) {
        int p = atomicAdd(&ws[WS_CURSOR + type_r[i]], 1);
        ws[WS_ORDER + p] = i;
    }
}

// ---------------- main kernel ----------------
// block = 256 threads: thread (c2 = tid&63, q = tid>>6) owns columns
// {c2, c2+64} x rows [32q, 32q+32) of T (64 VGPRs of T per thread).

__global__ __launch_bounds__(256) void transr_grouped_kernel(
    const float* __restrict__ ent,
    const float* __restrict__ rel,
    const float* __restrict__ tmat,
    const int* __restrict__ pos_h,
    const int* __restrict__ pos_t,
    const int* __restrict__ pos_r,
    const int* __restrict__ neg_h,
    const int* __restrict__ neg_t,
    const int* __restrict__ neg_r,
    const int* __restrict__ ws,
    float* __restrict__ out,
    float inv_B)
{
    const int nit = ws[WS_NITEMS];
    if (blockIdx.x >= nit) return;
    const int4 item = ((const int4*)(ws + WS_ITEMS))[blockIdx.x];
    const int type  = item.x;
    const int start = item.y;
    const int cnt   = item.z;

    const int tid = threadIdx.x;
    const int c2  = tid & 63;
    const int q   = tid >> 6;

    __shared__ float4 vbuf[2][D];      // {ph,pt,nh,nt}[d], double-buffered
    __shared__ float  relP[2][D];
    __shared__ float  relN[2][D];
    __shared__ float4 pacc[4 * D];     // per-q partial dots, 4 vecs per col

    const int* order = ws + WS_ORDER;

    // prefetch sample 0
    float4 rv = make_float4(0.f, 0.f, 0.f, 0.f);
    float rp = 0.f, rn = 0.f;
    {
        const int idx = order[start];
        if (tid < D) {
            rv.x = ent[(size_t)pos_h[idx] * D + tid];
            rv.y = ent[(size_t)pos_t[idx] * D + tid];
            rv.z = ent[(size_t)neg_h[idx] * D + tid];
            rv.w = ent[(size_t)neg_t[idx] * D + tid];
        } else {
            const int t2 = tid - D;
            rp = rel[(size_t)pos_r[idx] * D + t2];
            rn = rel[(size_t)neg_r[idx] * D + t2];
        }
    }

    // T into registers
    float ta[32], tb[32];
    {
        const float* Tp = tmat + (size_t)type * (D * D) + (size_t)(q * 32) * D + c2;
        #pragma unroll
        for (int dd = 0; dd < 32; ++dd) {
            ta[dd] = Tp[dd * D];
            tb[dd] = Tp[dd * D + 64];
        }
    }

    int cur = 0;
    float loss_acc = 0.f;

    for (int j = 0; j < cnt; ++j) {
        // commit prefetched sample j
        if (tid < D) vbuf[cur][tid] = rv;
        else { relP[cur][tid - D] = rp; relN[cur][tid - D] = rn; }

        // issue prefetch for sample j+1
        if (j + 1 < cnt) {
            const int idx = order[start + j + 1];
            if (tid < D) {
                rv.x = ent[(size_t)pos_h[idx] * D + tid];
                rv.y = ent[(size_t)pos_t[idx] * D + tid];
                rv.z = ent[(size_t)neg_h[idx] * D + tid];
                rv.w = ent[(size_t)neg_t[idx] * D + tid];
            } else {
                const int t2 = tid - D;
                rp = rel[(size_t)pos_r[idx] * D + t2];
                rn = rel[(size_t)neg_r[idx] * D + t2];
            }
        }
        __syncthreads();   // B1: vbuf[cur]/rel[cur] visible; prev pacc reads done

        float a0 = 0.f, a1 = 0.f, a2 = 0.f, a3 = 0.f;
        float b0 = 0.f, b1 = 0.f, b2 = 0.f, b3 = 0.f;
        #pragma unroll
        for (int dd = 0; dd < 32; ++dd) {
            const float4 v = vbuf[cur][(q << 5) + dd];
            a0 = fmaf(v.x, ta[dd], a0);
            a1 = fmaf(v.y, ta[dd], a1);
            a2 = fmaf(v.z, ta[dd], a2);
            a3 = fmaf(v.w, ta[dd], a3);
            b0 = fmaf(v.x, tb[dd], b0);
            b1 = fmaf(v.y, tb[dd], b1);
            b2 = fmaf(v.z, tb[dd], b2);
            b3 = fmaf(v.w, tb[dd], b3);
        }
        pacc[q * D + c2]      = make_float4(a0, a1, a2, a3);
        pacc[q * D + c2 + 64] = make_float4(b0, b1, b2, b3);
        __syncthreads();   // B2: pacc visible

        if (q == 0) {
            float4 hA = pacc[c2];
            float4 hB = pacc[c2 + 64];
            #pragma unroll
            for (int k = 1; k < 4; ++k) {
                const float4 tA = pacc[k * D + c2];
                const float4 tB = pacc[k * D + c2 + 64];
                hA.x += tA.x; hA.y += tA.y; hA.z += tA.z; hA.w += tA.w;
                hB.x += tB.x; hB.y += tB.y; hB.z += tB.z; hB.w += tB.w;
            }
            const float pA = relP[cur][c2], pB = relP[cur][c2 + 64];
            const float nA = relN[cur][c2], nB = relN[cur][c2 + 64];

            float s0 = hA.x * hA.x + hB.x * hB.x;   // |p_h_|^2
            float s1 = hA.y * hA.y + hB.y * hB.y;   // |p_t_|^2
            float s2 = hA.z * hA.z + hB.z * hB.z;   // |n_h_|^2
            float s3 = hA.w * hA.w + hB.w * hB.w;   // |n_t_|^2
            float s4 = pA * pA + pB * pB;           // |p_r|^2
            float s5 = nA * nA + nB * nB;           // |n_r|^2
            #pragma unroll
            for (int m = 1; m < 64; m <<= 1) {
                s0 += __shfl_xor(s0, m);
                s1 += __shfl_xor(s1, m);
                s2 += __shfl_xor(s2, m);
                s3 += __shfl_xor(s3, m);
                s4 += __shfl_xor(s4, m);
                s5 += __shfl_xor(s5, m);
            }
            const float iph = rsqrtf(s0 + 1e-12f);
            const float ipt = rsqrtf(s1 + 1e-12f);
            const float inh = rsqrtf(s2 + 1e-12f);
            const float itn = rsqrtf(s3 + 1e-12f);
            const float ipr = rsqrtf(s4 + 1e-12f);
            const float inr = rsqrtf(s5 + 1e-12f);

            float pterm = fabsf(hA.x * iph + pA * ipr - hA.y * ipt)
                        + fabsf(hB.x * iph + pB * ipr - hB.y * ipt);
            float nterm = fabsf(hA.z * inh + nA * inr - hA.w * itn)
                        + fabsf(hB.z * inh + nB * inr - hB.w * itn);
            #pragma unroll
            for (int m = 1; m < 64; m <<= 1) {
                pterm += __shfl_xor(pterm, m);
                nterm += __shfl_xor(nterm, m);
            }
            loss_acc += fmaxf(pterm - nterm + MARGIN, 0.f);
        }
        cur ^= 1;
    }

    if (tid == 0) atomicAdd(out, loss_acc * inv_B);
}

// ---------------- round-1 fallback (correct, 145us) ----------------

__global__ __launch_bounds__(128) void transr_loss_kernel(
    const float* __restrict__ ent, const float* __restrict__ rel,
    const float* __restrict__ tmat,
    const int* __restrict__ pos_h, const int* __restrict__ pos_t,
    const int* __restrict__ pos_r, const int* __restrict__ pos_type_r,
    const int* __restrict__ neg_h, const int* __restrict__ neg_t,
    const int* __restrict__ neg_r, float* __restrict__ out, int B)
{
    const int b = blockIdx.x;
    const int r = threadIdx.x;
    const int lane = r & 63;
    const int wid = r >> 6;
    __shared__ float4 vcomb[D];
    __shared__ float sred[16];
    const float* ph = ent + (size_t)pos_h[b] * D;
    const float* pt = ent + (size_t)pos_t[b] * D;
    const float* nh = ent + (size_t)neg_h[b] * D;
    const float* nt = ent + (size_t)neg_t[b] * D;
    vcomb[r] = make_float4(ph[r], pt[r], nh[r], nt[r]);
    const float prr = rel[(size_t)pos_r[b] * D + r];
    const float nrr = rel[(size_t)neg_r[b] * D + r];
    __syncthreads();
    const float* __restrict__ T = tmat + (size_t)pos_type_r[b] * (D * D);
    float aph = 0.f, apt = 0.f, anh = 0.f, ant = 0.f;
    #pragma unroll 8
    for (int d = 0; d < D; ++d) {
        const float t = T[d * D + r];
        const float4 v = vcomb[d];
        aph = fmaf(v.x, t, aph); apt = fmaf(v.y, t, apt);
        anh = fmaf(v.z, t, anh); ant = fmaf(v.w, t, ant);
    }
    float s0 = aph*aph, s1 = apt*apt, s2 = anh*anh, s3 = ant*ant;
    float s4 = prr*prr, s5 = nrr*nrr;
    #pragma unroll
    for (int off = 32; off; off >>= 1) {
        s0 += __shfl_xor(s0, off); s1 += __shfl_xor(s1, off);
        s2 += __shfl_xor(s2, off); s3 += __shfl_xor(s3, off);
        s4 += __shfl_xor(s4, off); s5 += __shfl_xor(s5, off);
    }
    if (lane == 0) {
        sred[wid*8+0]=s0; sred[wid*8+1]=s1; sred[wid*8+2]=s2;
        sred[wid*8+3]=s3; sred[wid*8+4]=s4; sred[wid*8+5]=s5;
    }
    __syncthreads();
    const float iph = rsqrtf(sred[0]+sred[8] +1e-12f);
    const float ipt = rsqrtf(sred[1]+sred[9] +1e-12f);
    const float inh = rsqrtf(sred[2]+sred[10]+1e-12f);
    const float itn = rsqrtf(sred[3]+sred[11]+1e-12f);
    const float ipr = rsqrtf(sred[4]+sred[12]+1e-12f);
    const float inr = rsqrtf(sred[5]+sred[13]+1e-12f);
    float pterm = fabsf(aph*iph + prr*ipr - apt*ipt);
    float nterm = fabsf(anh*inh + nrr*inr - ant*itn);
    #pragma unroll
    for (int off = 32; off; off >>= 1) {
        pterm += __shfl_xor(pterm, off);
        nterm += __shfl_xor(nterm, off);
    }
    __syncthreads();
    if (lane == 0) { sred[wid*2+0] = pterm; sred[wid*2+1] = nterm; }
    __syncthreads();
    if (r == 0) {
        const float p = sred[0] + sred[2];
        const float n = sred[1] + sred[3];
        atomicAdd(out, fmaxf(p - n + MARGIN, 0.f) / (float)B);
    }
}

// ---------------- launch ----------------

extern "C" void kernel_launch(void* const* d_in, const int* in_sizes, int n_in,
                              void* d_out, int out_size, void* d_ws, size_t ws_size,
                              hipStream_t stream) {
    const float* ent  = (const float*)d_in[0];
    const float* rel  = (const float*)d_in[1];
    const float* tmat = (const float*)d_in[2];
    const int* pos_h      = (const int*)d_in[3];
    const int* pos_t      = (const int*)d_in[4];
    const int* pos_r      = (const int*)d_in[5];
    const int* pos_type_r = (const int*)d_in[6];
    const int* neg_h      = (const int*)d_in[7];
    const int* neg_t      = (const int*)d_in[8];
    const int* neg_r      = (const int*)d_in[9];
    float* out = (float*)d_out;
    const int B = in_sizes[3];
    const int ntype = in_sizes[2] / (D * D);

    hipMemsetAsync(out, 0, sizeof(float), stream);

    if (ws_size < WS_NEEDED || ntype > MAX_TYPES || B > 8192) {
        // fallback: per-sample kernel
        transr_loss_kernel<<<B, 128, 0, stream>>>(
            ent, rel, tmat, pos_h, pos_t, pos_r, pos_type_r,
            neg_h, neg_t, neg_r, out, B);
        return;
    }

    int* ws = (int*)d_ws;
    hipMemsetAsync(ws, 0, MAX_TYPES * sizeof(int), stream);   // counts
    hist_kernel<<<(B + 255) / 256, 256, 0, stream>>>(pos_type_r, ws, B);
    scan_kernel<<<1, 1024, 0, stream>>>(ws, ntype);
    scatter_kernel<<<(B + 255) / 256, 256, 0, stream>>>(pos_type_r, ws, B);
    transr_grouped_kernel<<<MAX_ITEMS, 256, 0, stream>>>(
        ent, rel, tmat, pos_h, pos_t, pos_r, neg_h, neg_t, neg_r,
        ws, out, 1.0f / (float)B);
}